// Round 14
// baseline (221.419 us; speedup 1.0000x reference)
//
#include <hip/hip_runtime.h>
#include <hip/hip_bf16.h>

#define B_ 128
#define H_ 1024
#define L_ 60
#define V_ 50257
#define NPB_ 786           // proj blocks (64 cols each)
#define NMP_ (NPB_ * 4)    // pms entries per row (16-col granules)

typedef __attribute__((ext_vector_type(8))) short bf16x8;
typedef __attribute__((ext_vector_type(4))) float f32x4;

__device__ __forceinline__ unsigned short f2bf(float f) {
  union { __hip_bfloat16 h; unsigned short u; } v;
  v.h = __float2bfloat16(f);
  return v.u;
}

__device__ __forceinline__ bf16x8 cvt8(float4 a, float4 b) {
  union { bf16x8 v; __hip_bfloat16 h[8]; } u;
  u.h[0] = __float2bfloat16(a.x); u.h[1] = __float2bfloat16(a.y);
  u.h[2] = __float2bfloat16(a.z); u.h[3] = __float2bfloat16(a.w);
  u.h[4] = __float2bfloat16(b.x); u.h[5] = __float2bfloat16(b.y);
  u.h[6] = __float2bfloat16(b.z); u.h[7] = __float2bfloat16(b.w);
  return u.v;
}

__device__ __forceinline__ void gl_lds16(const void* g, void* l) {
  __builtin_amdgcn_global_load_lds(
      (const __attribute__((address_space(1))) unsigned int*)g,
      (__attribute__((address_space(3))) unsigned int*)l, 16, 0, 0);
}

#define SBAR()   __builtin_amdgcn_s_barrier()
#define SCHED0() __builtin_amdgcn_sched_barrier(0)
__device__ __forceinline__ void lwait0() { asm volatile("s_waitcnt lgkmcnt(0)" ::: "memory"); }
__device__ __forceinline__ void vwait2() { asm volatile("s_waitcnt vmcnt(2)" ::: "memory"); }
__device__ __forceinline__ void vwait0() { asm volatile("s_waitcnt vmcnt(0)" ::: "memory"); }

// bf16 A-fragment pack position for MFMA 16x16x32 (verified R1-R13):
// fragment ((s*8+bm)*64+lane), elem j ; lane holds A[row=(bm*16)+(l&15)][k=s*32+(l>>4)*8+j]
__device__ __forceinline__ size_t packIdx(int b, int k) {
  int s = k >> 5;
  int bm = b >> 4;
  int lane = (b & 15) | (((k >> 3) & 3) << 4);
  return ((size_t)((s * 8 + bm) * 64 + lane) << 3) | (size_t)(k & 7);
}

// ------------- fused front: pack embedded+hidden (bx<512) | attn logits -------------
__global__ __launch_bounds__(256) void k_front(
    const int* __restrict__ input, const float* __restrict__ hidden,
    const float* __restrict__ emb, const float* __restrict__ attn_W,
    const float* __restrict__ attn_b, unsigned short* __restrict__ aXa,
    unsigned short* __restrict__ aH, float* __restrict__ lbuf)
{
  int bx = blockIdx.x;
  if (bx < 512) {
    int idx = bx * 256 + threadIdx.x;          // B_*H_
    int b = idx >> 10, j = idx & (H_ - 1);
    float e = emb[(size_t)input[b] * H_ + j];
    float h = hidden[idx];
    size_t p = packIdx(b, j);
    aXa[p] = f2bf(e);
    aH[p]  = f2bf(h);
  } else {
    int t = threadIdx.x, wv = t >> 6, lane = t & 63;
    int task = (bx - 512) * 4 + wv;            // 0 .. B_*L_-1
    int b = task / L_, l = task - b * L_;
    const float* erow = emb + (size_t)input[b] * H_;
    const float* hrow = hidden + (size_t)b * H_;
    const float* wr = attn_W + (size_t)l * (2 * H_);
    float acc = 0.f;
    #pragma unroll 4
    for (int i = 0; i < 16; ++i) {
      int m = lane + i * 64;
      acc += erow[m] * wr[m] + hrow[m] * wr[H_ + m];
    }
    #pragma unroll
    for (int off = 32; off; off >>= 1) acc += __shfl_xor(acc, off);
    if (lane == 0) lbuf[b * 64 + l] = acc + attn_b[l];
  }
}

// ------------- attn softmax (redundant per block) + weighted sum + pack -------------
__global__ __launch_bounds__(256) void k_appsm(
    const float* __restrict__ enc, const float* __restrict__ lbuf,
    float* __restrict__ attnw, unsigned short* __restrict__ aXa)
{
  __shared__ float sWt[64];
  int b = blockIdx.x, q = blockIdx.y, t = threadIdx.x;
  if (t < 64) {
    float v = (t < L_) ? lbuf[b * 64 + t] : -1e30f;
    float m = v;
    #pragma unroll
    for (int off = 32; off; off >>= 1) m = fmaxf(m, __shfl_xor(m, off));
    float e = (t < L_) ? __expf(v - m) : 0.f;
    float s = e;
    #pragma unroll
    for (int off = 32; off; off >>= 1) s += __shfl_xor(s, off);
    float w = e / s;
    sWt[t] = w;
    if (q == 0 && t < L_) attnw[b * L_ + t] = w;
  }
  __syncthreads();
  int col = q * 256 + t;
  const float* eb = enc + (size_t)b * L_ * H_ + col;
  float acc = 0.f;
  #pragma unroll 4
  for (int l = 0; l < L_; ++l) acc += sWt[l] * eb[(size_t)l * H_];
  aXa[packIdx(b, H_ + col)] = f2bf(acc);
}

// ------------- R7 GEMM (comb / gi|gh): reg-staged W, bf16 LDS, 1 barrier/chunk -------
__global__ __launch_bounds__(256, 4) void k_gemm(
    const unsigned short* __restrict__ Apk, const unsigned short* __restrict__ Apk2,
    const float* __restrict__ Wt, const float* __restrict__ Wt2,
    float* __restrict__ Cpart, float* __restrict__ Cpart2,
    int K, int N, int nchunks, int halfY)
{
  __shared__ __align__(16) unsigned short bufW0[64 * 32];   // 4KB bf16
  __shared__ __align__(16) unsigned short bufW1[64 * 32];   // 4KB bf16
  int t = threadIdx.x, wv = t >> 6, lane = t & 63;
  int y = blockIdx.y;
  const unsigned short* A = Apk;
  const float* W = Wt;
  float* CP = Cpart;
  int sidx = y;
  if (halfY && y >= halfY) { A = Apk2; W = Wt2; CP = Cpart2; sidx = y - halfY; }
  int chunk0 = sidx * nchunks;
  int n0 = blockIdx.x * 64;
  int ch = wv & 1;
  int bm0 = (wv >> 1) * 4;
  int g = lane >> 4;

  int sr  = wv * 16 + (lane >> 2);
  int sj  = lane & 3;
  int ssl = sj ^ ((sr >> 1) & 3);
  int sgcol = n0 + sr; sgcol = (sgcol < N) ? sgcol : (N - 1);
  const float* wsrc = W + (size_t)sgcol * K + sj * 8;
  unsigned short* wdst0 = &bufW0[sr * 32 + ssl * 8];
  unsigned short* wdst1 = &bufW1[sr * 32 + ssl * 8];

  f32x4 acc[4][2];
  #pragma unroll
  for (int i = 0; i < 4; ++i)
    #pragma unroll
    for (int j = 0; j < 2; ++j) acc[i][j] = (f32x4){0.f, 0.f, 0.f, 0.f};

  auto GW = [&](int kc, float4& lo, float4& hi) {
    const float* p = wsrc + (size_t)kc * 32;
    lo = *(const float4*)p;
    hi = *(const float4*)(p + 4);
  };
  const bf16x8* apg = (const bf16x8*)A;
  auto LA = [&](int kc, bf16x8* x) {
    #pragma unroll
    for (int j = 0; j < 4; ++j)
      x[j] = apg[((size_t)kc * 8 + bm0 + j) * 64 + lane];
  };
  auto COMP = [&](const unsigned short* buf, const bf16x8* a) {
    #pragma unroll
    for (int nci = 0; nci < 2; ++nci) {
      int rr = (ch * 2 + nci) * 16 + (lane & 15);
      int s = g ^ ((rr >> 1) & 3);
      bf16x8 bfr = *(const bf16x8*)&buf[rr * 32 + s * 8];
      #pragma unroll
      for (int j = 0; j < 4; ++j)
        acc[j][nci] = __builtin_amdgcn_mfma_f32_16x16x32_bf16(a[j], bfr, acc[j][nci], 0, 0, 0);
    }
  };

  float4 lo0, hi0, lo1, hi1;
  bf16x8 aA[4], aB[4];
  GW(chunk0, lo0, hi0); LA(chunk0, aA);

  for (int kk = 0; kk < nchunks; kk += 2) {
    if (kk + 1 < nchunks) { GW(chunk0 + kk + 1, lo1, hi1); LA(chunk0 + kk + 1, aB); }
    *(bf16x8*)wdst0 = cvt8(lo0, hi0);
    lwait0(); SCHED0(); SBAR(); SCHED0();
    COMP(bufW0, aA);
    if (kk + 1 >= nchunks) break;
    if (kk + 2 < nchunks) { GW(chunk0 + kk + 2, lo0, hi0); LA(chunk0 + kk + 2, aA); }
    *(bf16x8*)wdst1 = cvt8(lo1, hi1);
    lwait0(); SCHED0(); SBAR(); SCHED0();
    COMP(bufW1, aB);
  }

  float* dst = CP + (size_t)sidx * B_ * N;
  int rb = (lane >> 4) * 4;
  #pragma unroll
  for (int bm = 0; bm < 4; ++bm)
    #pragma unroll
    for (int r = 0; r < 4; ++r) {
      int row = (bm0 + bm) * 16 + rb + r;
      #pragma unroll
      for (int nci = 0; nci < 2; ++nci) {
        int c = n0 + (ch * 2 + nci) * 16 + (lane & 15);
        if (c < N) dst[(size_t)row * N + c] = acc[bm][nci][r];
      }
    }
}

// ------------- proj GEMM: ZERO-BARRIER wave-private gl_lds streaming -------------
// C[b,n] = sum_k A[b,k]*W[n,k], K=1024, 32 chunks of 32k. Block = 64 cols, 4 waves;
// wave cg owns cols n0+cg*16..+16 PRIVATELY: stages its own W (16 rows x 128B =
// 2KB/chunk) into its own 4KB LDS slice via global_load_lds (HW queue = pipeline,
// no VGPR-depth collapse), depth-1, paced by s_waitcnt vmcnt(2) -- NO s_barrier
// in the whole kernel. All 786 blocks resident ((256,6), ~24 waves/CU), every
// wave free-running => TLP covers memory latency (the property all R3-R13
// variants lacked). A-frags: 8/chunk direct bf16 loads (L2), single set, issued
// BEFORE STAGE(c+1) so compiler's A-wait = vmcnt(2) (never waits next-chunk W).
// Source-XOR granule swizzle g^(row&6) keeps pairs adjacent -> b128 reads.
// XCD-bijective block swizzle: each XCD streams a contiguous ~25MB W slab.
__global__ __launch_bounds__(256, 6) void k_proj(
    const unsigned short* __restrict__ Apk, const float* __restrict__ W,
    const float* __restrict__ bias, float* __restrict__ logits,
    float* __restrict__ pms)
{
  __shared__ __align__(16) float lds[4][2][512];   // [wave][buf][2KB f32]
  int t = threadIdx.x, w = t >> 6, lane = t & 63;
  // bijective XCD swizzle over NPB_=786 (q=98, r=2)
  int bid = blockIdx.x;
  int qq8 = NPB_ / 8, r8 = NPB_ % 8;
  int xcd = bid & 7, sub = bid >> 3;
  int blk = (xcd < r8 ? xcd * (qq8 + 1) : r8 * (qq8 + 1) + (xcd - r8) * qq8) + sub;
  int n0 = blk * 64;
  int cg = w;
  // staging coords: call i covers rows i*8..i*8+7; lane -> row (l>>3), granule l&7
  int srow = lane >> 3, sg = lane & 7;
  // compute coords
  int rr = lane & 15, qg = lane >> 4;
  int pp = (qg ^ ((rr >> 1) & 3)) * 8;       // physical float offset of 32B pair

  const bf16x8* apg = (const bf16x8*)Apk;

  f32x4 acc[8];
  #pragma unroll
  for (int i = 0; i < 8; ++i) acc[i] = (f32x4){0.f, 0.f, 0.f, 0.f};

  auto STAGE = [&](int kc, int buf) {
    #pragma unroll
    for (int i = 0; i < 2; ++i) {
      int rw = i * 8 + srow;
      int col = n0 + cg * 16 + rw; if (col >= V_) col = V_ - 1;
      int gs = sg ^ (rw & 6);
      const float* src = W + (size_t)col * H_ + kc * 32 + gs * 4;
      gl_lds16(src, &lds[w][buf][i * 256]);
    }
  };
  bf16x8 aA[8];
  auto LA = [&](int kc) {
    #pragma unroll
    for (int bm = 0; bm < 8; ++bm)
      aA[bm] = apg[((size_t)kc * 8 + bm) * 64 + lane];
  };
  auto COMP = [&](int buf) {
    const float* bw = &lds[w][buf][0];
    float4 lo = *(const float4*)&bw[rr * 32 + pp];
    float4 hi = *(const float4*)&bw[rr * 32 + pp + 4];
    bf16x8 bfr = cvt8(lo, hi);
    #pragma unroll
    for (int bm = 0; bm < 8; ++bm)
      acc[bm] = __builtin_amdgcn_mfma_f32_16x16x32_bf16(aA[bm], bfr, acc[bm], 0, 0, 0);
  };

  STAGE(0, 0);
  for (int c = 0; c < 32; c += 2) {
    LA(c);
    if (c + 1 < 32) STAGE(c + 1, 1);
    vwait2(); SCHED0();
    COMP(0);
    SCHED0();
    LA(c + 1);
    if (c + 2 < 32) STAGE(c + 2, 0);
    if (c + 2 < 32) vwait2(); else vwait0();
    SCHED0();
    COMP(1);
    SCHED0();
  }

  // epilogue: C-write + fused softmax partials (wave covers full 16-col granule)
  int col = n0 + cg * 16 + rr;
  float bv = (col < V_) ? bias[col] : 0.f;
  #pragma unroll
  for (int bm = 0; bm < 8; ++bm)
    #pragma unroll
    for (int r = 0; r < 4; ++r) {
      int row = bm * 16 + qg * 4 + r;
      float v = acc[bm][r] + bv;
      if (col < V_) logits[(size_t)row * V_ + col] = v;
      float m = (col < V_) ? v : -1e30f;
      #pragma unroll
      for (int off = 8; off; off >>= 1) m = fmaxf(m, __shfl_xor(m, off));
      float e = (col < V_) ? __expf(v - m) : 0.f;
      #pragma unroll
      for (int off = 8; off; off >>= 1) e += __shfl_xor(e, off);
      if (rr == 0) {
        size_t o = ((size_t)row * NMP_ + blk * 4 + cg) * 2;
        pms[o] = m; pms[o + 1] = e;
      }
    }
}

// ------------- reduce combine partials (16) + bias + relu -> packed x -------------
__global__ __launch_bounds__(256) void k_reduce_comb(
    const float* __restrict__ parts, const float* __restrict__ bias,
    unsigned short* __restrict__ aX)
{
  int idx = blockIdx.x * 256 + threadIdx.x;  // B_*H_
  int b = idx >> 10, j = idx & (H_ - 1);
  float s = bias[j];
  #pragma unroll
  for (int p = 0; p < 16; ++p) s += parts[(size_t)p * B_ * H_ + idx];
  s = fmaxf(s, 0.f);
  aX[packIdx(b, j)] = f2bf(s);
}

// ------------- GRU gates from split partials (4+4) -> h_new (+packed) -------------
__global__ __launch_bounds__(256) void k_gate(
    const float* __restrict__ giP, const float* __restrict__ ghP,
    const float* __restrict__ b_ih, const float* __restrict__ b_hh,
    const float* __restrict__ hidden, float* __restrict__ hnew,
    unsigned short* __restrict__ aHn)
{
  int idx = blockIdx.x * 256 + threadIdx.x;  // B_*H_
  int b = idx >> 10, j = idx & (H_ - 1);
  size_t base = (size_t)b * 3 * H_;
  float ir = b_ih[j], iz = b_ih[H_ + j], in_ = b_ih[2 * H_ + j];
  float hr = b_hh[j], hz = b_hh[H_ + j], hn = b_hh[2 * H_ + j];
  #pragma unroll
  for (int p = 0; p < 4; ++p) {
    const float* gi = giP + (size_t)p * B_ * 3 * H_ + base;
    const float* gh = ghP + (size_t)p * B_ * 3 * H_ + base;
    ir += gi[j]; iz += gi[H_ + j]; in_ += gi[2 * H_ + j];
    hr += gh[j]; hz += gh[H_ + j]; hn += gh[2 * H_ + j];
  }
  float r = 1.f / (1.f + __expf(-(ir + hr)));
  float z = 1.f / (1.f + __expf(-(iz + hz)));
  float n = tanhf(in_ + r * hn);
  float h = hidden[idx];
  float hv = (1.f - z) * n + z * h;
  hnew[idx] = hv;
  aHn[packIdx(b, j)] = f2bf(hv);
}

// ------------- log_softmax: per-block redundant reduce of pms + subtract -------------
#define SL_ 6283
__global__ __launch_bounds__(256) void k_lsub(
    float* __restrict__ logits, const float* __restrict__ pms, int nblk2)
{
  __shared__ float sm[4], ss[4], sc;
  int b = blockIdx.x, sl = blockIdx.y, t = threadIdx.x;
  float M = -1e30f, S = 0.f;
  for (int i = t; i < nblk2; i += 256) {
    float m = pms[((size_t)b * nblk2 + i) * 2];
    float s = pms[((size_t)b * nblk2 + i) * 2 + 1];
    float nm = fmaxf(M, m);
    S = S * __expf(M - nm) + s * __expf(m - nm);
    M = nm;
  }
  #pragma unroll
  for (int off = 32; off; off >>= 1) {
    float m2 = __shfl_xor(M, off), s2 = __shfl_xor(S, off);
    float nm = fmaxf(M, m2);
    S = S * __expf(M - nm) + s2 * __expf(m2 - nm);
    M = nm;
  }
  if ((t & 63) == 0) { sm[t >> 6] = M; ss[t >> 6] = S; }
  __syncthreads();
  if (t == 0) {
    float Mf = sm[0], Sf = ss[0];
    #pragma unroll
    for (int i = 1; i < 4; ++i) {
      float nm = fmaxf(Mf, sm[i]);
      Sf = Sf * __expf(Mf - nm) + ss[i] * __expf(sm[i] - nm);
      Mf = nm;
    }
    sc = Mf + logf(Sf);
  }
  __syncthreads();
  float c = sc;
  int v0 = sl * SL_;
  int v1 = v0 + SL_; if (v1 > V_) v1 = V_;
  float* row = logits + (size_t)b * V_;
  for (int v = v0 + t; v < v1; v += 256) row[v] -= c;
}

extern "C" void kernel_launch(void* const* d_in, const int* in_sizes, int n_in,
                              void* d_out, int out_size, void* d_ws, size_t ws_size,
                              hipStream_t stream)
{
  const int*   input  = (const int*)d_in[0];
  const float* hidden = (const float*)d_in[1];
  const float* enc    = (const float*)d_in[2];
  const float* emb    = (const float*)d_in[3];
  const float* attn_W = (const float*)d_in[4];
  const float* attn_b = (const float*)d_in[5];
  const float* comb_W = (const float*)d_in[6];
  const float* comb_b = (const float*)d_in[7];
  const float* W_ih   = (const float*)d_in[8];
  const float* W_hh   = (const float*)d_in[9];
  const float* b_ih   = (const float*)d_in[10];
  const float* b_hh   = (const float*)d_in[11];
  const float* out_W  = (const float*)d_in[12];
  const float* out_b  = (const float*)d_in[13];

  float* out    = (float*)d_out;
  float* logits = out;                        // [B,V]
  float* hnew   = out + (size_t)B_ * V_;      // [1,B,H]
  float* attnw  = hnew + (size_t)B_ * H_;     // [B,L]

  char* ws = (char*)d_ws;
  unsigned short* aXa = (unsigned short*)(ws);                 // 512K
  unsigned short* aH  = (unsigned short*)(ws + 524288);        // 256K
  unsigned short* aX  = (unsigned short*)(ws + 786432);        // 256K
  unsigned short* aHn = (unsigned short*)(ws + 1048576);       // 256K
  float* lbuf  = (float*)(ws + 1310720);                       // 32K
  float* pms   = (float*)(ws + 1343488);                       // 3.22M (128*3144*8B)
  // scratch (aliased): combP (16 x 512K) consumed by k_reduce_comb BEFORE
  // giP/ghP produced by the gi|gh GEMM.
  float* combP = (float*)(ws + 4587520);                       // 8MB
  float* giP   = (float*)(ws + 4587520);                       // 6MB (aliases combP)
  float* ghP   = (float*)(ws + 4587520 + 6291456);             // 6MB

  // 1. fused: pack embedded+hidden | attention logits
  k_front<<<512 + (B_ * L_) / 4, 256, 0, stream>>>(input, hidden, emb, attn_W, attn_b,
                                                   aXa, aH, lbuf);
  // 2. softmax (redundant per block) + weighted sum; pack into aXa hi
  k_appsm<<<dim3(B_, 4), 256, 0, stream>>>(enc, lbuf, attnw, aXa);
  // 3. combine GEMM: K=2048 (64 chunks), 16 splits x 4 chunks
  k_gemm<<<dim3(16, 16), 256, 0, stream>>>(aXa, nullptr, comb_W, nullptr,
                                           combP, nullptr, 2 * H_, H_, 4, 0);
  // 4. reduce + bias + relu -> packed x
  k_reduce_comb<<<(B_ * H_) / 256, 256, 0, stream>>>(combP, comb_b, aX);
  // 5. fused gi|gh GEMMs: K=1024 (32 chunks), each 4 splits x 8 chunks
  k_gemm<<<dim3(48, 8), 256, 0, stream>>>(aX, aH, W_ih, W_hh,
                                          giP, ghP, H_, 3 * H_, 8, 4);
  // 6. gates -> h_new (out) + packed h_new
  k_gate<<<(B_ * H_) / 256, 256, 0, stream>>>(giP, ghP, b_ih, b_hh, hidden, hnew, aHn);
  // 7. projection: zero-barrier wave-private gl_lds streaming + softmax partials
  k_proj<<<NPB_, 256, 0, stream>>>(aHn, out_W, out_b, logits, pms);
  // 8. fused reduce + subtract (NMP_ partials per row)
  k_lsub<<<dim3(B_, 8), 256, 0, stream>>>(logits, pms, NMP_);
}

// Round 15
// 130.973 us; speedup vs baseline: 1.6906x; 1.6906x over previous
//
#include <hip/hip_runtime.h>
#include <hip/hip_bf16.h>

#define B_ 128
#define H_ 1024
#define L_ 60
#define V_ 50257

typedef __attribute__((ext_vector_type(8))) short bf16x8;
typedef __attribute__((ext_vector_type(4))) float f32x4;

__device__ __forceinline__ unsigned short f2bf(float f) {
  union { __hip_bfloat16 h; unsigned short u; } v;
  v.h = __float2bfloat16(f);
  return v.u;
}

__device__ __forceinline__ bf16x8 cvt8(float4 a, float4 b) {
  union { bf16x8 v; __hip_bfloat16 h[8]; } u;
  u.h[0] = __float2bfloat16(a.x); u.h[1] = __float2bfloat16(a.y);
  u.h[2] = __float2bfloat16(a.z); u.h[3] = __float2bfloat16(a.w);
  u.h[4] = __float2bfloat16(b.x); u.h[5] = __float2bfloat16(b.y);
  u.h[6] = __float2bfloat16(b.z); u.h[7] = __float2bfloat16(b.w);
  return u.v;
}

__device__ __forceinline__ void gl_lds16(const void* g, void* l) {
  __builtin_amdgcn_global_load_lds(
      (const __attribute__((address_space(1))) unsigned int*)g,
      (__attribute__((address_space(3))) unsigned int*)l, 16, 0, 0);
}

#define SBAR()   __builtin_amdgcn_s_barrier()
#define SCHED0() __builtin_amdgcn_sched_barrier(0)
__device__ __forceinline__ void vwait6() { asm volatile("s_waitcnt vmcnt(6)" ::: "memory"); }
__device__ __forceinline__ void vwait0() { asm volatile("s_waitcnt vmcnt(0)" ::: "memory"); }

// bf16 A-fragment pack position for MFMA 16x16x32 (verified R1-R14):
// fragment ((s*8+bm)*64+lane), elem j ; lane holds A[row=(bm*16)+(l&15)][k=s*32+(l>>4)*8+j]
__device__ __forceinline__ size_t packIdx(int b, int k) {
  int s = k >> 5;
  int bm = b >> 4;
  int lane = (b & 15) | (((k >> 3) & 3) << 4);
  return ((size_t)((s * 8 + bm) * 64 + lane) << 3) | (size_t)(k & 7);
}

// ------------- fused front: pack embedded+hidden (bx<512) | attn logits -------------
__global__ __launch_bounds__(256) void k_front(
    const int* __restrict__ input, const float* __restrict__ hidden,
    const float* __restrict__ emb, const float* __restrict__ attn_W,
    const float* __restrict__ attn_b, unsigned short* __restrict__ aXa,
    unsigned short* __restrict__ aH, float* __restrict__ lbuf)
{
  int bx = blockIdx.x;
  if (bx < 512) {
    int idx = bx * 256 + threadIdx.x;          // B_*H_
    int b = idx >> 10, j = idx & (H_ - 1);
    float e = emb[(size_t)input[b] * H_ + j];
    float h = hidden[idx];
    size_t p = packIdx(b, j);
    aXa[p] = f2bf(e);
    aH[p]  = f2bf(h);
  } else {
    int t = threadIdx.x, wv = t >> 6, lane = t & 63;
    int task = (bx - 512) * 4 + wv;            // 0 .. B_*L_-1
    int b = task / L_, l = task - b * L_;
    const float* erow = emb + (size_t)input[b] * H_;
    const float* hrow = hidden + (size_t)b * H_;
    const float* wr = attn_W + (size_t)l * (2 * H_);
    float acc = 0.f;
    #pragma unroll 4
    for (int i = 0; i < 16; ++i) {
      int m = lane + i * 64;
      acc += erow[m] * wr[m] + hrow[m] * wr[H_ + m];
    }
    #pragma unroll
    for (int off = 32; off; off >>= 1) acc += __shfl_xor(acc, off);
    if (lane == 0) lbuf[b * 64 + l] = acc + attn_b[l];
  }
}

// ------------- attn softmax (redundant per block) + weighted sum + pack -------------
__global__ __launch_bounds__(256) void k_appsm(
    const float* __restrict__ enc, const float* __restrict__ lbuf,
    float* __restrict__ attnw, unsigned short* __restrict__ aXa)
{
  __shared__ float sWt[64];
  int b = blockIdx.x, q = blockIdx.y, t = threadIdx.x;
  if (t < 64) {
    float v = (t < L_) ? lbuf[b * 64 + t] : -1e30f;
    float m = v;
    #pragma unroll
    for (int off = 32; off; off >>= 1) m = fmaxf(m, __shfl_xor(m, off));
    float e = (t < L_) ? __expf(v - m) : 0.f;
    float s = e;
    #pragma unroll
    for (int off = 32; off; off >>= 1) s += __shfl_xor(s, off);
    float w = e / s;
    sWt[t] = w;
    if (q == 0 && t < L_) attnw[b * L_ + t] = w;
  }
  __syncthreads();
  int col = q * 256 + t;
  const float* eb = enc + (size_t)b * L_ * H_ + col;
  float acc = 0.f;
  #pragma unroll 4
  for (int l = 0; l < L_; ++l) acc += sWt[l] * eb[(size_t)l * H_];
  aXa[packIdx(b, H_ + col)] = f2bf(acc);
}

// ------------- LDS-staged MFMA GEMM, counted-vmcnt, wave = 64 rows x 32 cols -------------
// C[b,n] = sum_k A[b,k]*W[n,k]. Tile 128(B) x 64(N), chunk = 32 k.
// W: 8KB f32/chunk staged via global_load_lds (XOR-swizzled both sides), 2-buffered.
// A: per-wave 4 bm fragments global->VGPR, reg-double-buffered (static roles).
// Wave wv: rows [64*(wv>>1), +64) x cols [32*(wv&1), +32)  ->  B-side work 2x
// (vs 4x in the rows-only split): per chunk/wave 4 ds_read_b128 + 2 cvt8 + 8 MFMA.
// VMEM/chunk = 2 gl_lds + 4 A = 6 -> vwait6 == "previous chunk landed".
// Proven 2-barrier fence skeleton; vmcnt never drained mid-loop.
// Best-measured configuration (130.2 us total, R6/R7 bench).
__global__ __launch_bounds__(256, 5) void k_gemm(
    const unsigned short* __restrict__ Apk, const unsigned short* __restrict__ Apk2,
    const float* __restrict__ Wt, const float* __restrict__ Wt2,
    const float* __restrict__ bias, float* __restrict__ Cdir,
    float* __restrict__ Cpart, float* __restrict__ Cpart2,
    float* __restrict__ pms, int K, int N, int nchunks, int halfY, int nblkx)
{
  __shared__ __align__(16) float bufW0[64 * 32];   // 8KB
  __shared__ __align__(16) float bufW1[64 * 32];   // 8KB
  int t = threadIdx.x, wv = t >> 6, lane = t & 63;
  int y = blockIdx.y;
  const unsigned short* A = Apk;
  const float* W = Wt;
  float* CP = Cpart;
  int sidx = y;
  if (halfY && y >= halfY) { A = Apk2; W = Wt2; CP = Cpart2; sidx = y - halfY; }
  int chunk0 = sidx * nchunks;
  int n0 = blockIdx.x * 64;
  int ch = wv & 1;            // col half: nc in {2ch, 2ch+1}
  int bm0 = (wv >> 1) * 4;    // row quarter-base: 4 bms
  int srow8 = lane >> 3;
  int sch = lane & 7;
  int g = lane >> 4;

  f32x4 acc[4][2];
  #pragma unroll
  for (int i = 0; i < 4; ++i)
    #pragma unroll
    for (int j = 0; j < 2; ++j) acc[i][j] = (f32x4){0.f, 0.f, 0.f, 0.f};

  auto SW = [&](int kc, float* buf) {
    #pragma unroll
    for (int i = 0; i < 2; ++i) {
      int r = wv * 16 + i * 8 + srow8;
      int gcol = n0 + r; gcol = (gcol < N) ? gcol : (N - 1);
      int c = sch ^ (r & 7);
      const float* src = W + (size_t)gcol * K + (size_t)kc * 32 + c * 4;
      gl_lds16(src, buf + (wv * 16 + i * 8) * 32);
    }
  };
  const bf16x8* apg = (const bf16x8*)A;
  auto LA = [&](int kc, bf16x8* x) {
    #pragma unroll
    for (int j = 0; j < 4; ++j)
      x[j] = apg[((size_t)kc * 8 + bm0 + j) * 64 + lane];
  };
  auto COMP = [&](const float* bw, const bf16x8* a) {
    #pragma unroll
    for (int nci = 0; nci < 2; ++nci) {
      int rr = (ch * 2 + nci) * 16 + (lane & 15);
      int c0 = (g * 2) ^ (rr & 7);
      int c1 = (g * 2 + 1) ^ (rr & 7);
      float4 w0 = *(const float4*)&bw[rr * 32 + c0 * 4];
      float4 w1 = *(const float4*)&bw[rr * 32 + c1 * 4];
      bf16x8 bfr = cvt8(w0, w1);
      #pragma unroll
      for (int j = 0; j < 4; ++j)
        acc[j][nci] = __builtin_amdgcn_mfma_f32_16x16x32_bf16(a[j], bfr, acc[j][nci], 0, 0, 0);
    }
  };

  bf16x8 aA[4], aB[4];
  SW(chunk0, bufW0);     LA(chunk0, aA);
  SW(chunk0 + 1, bufW1); LA(chunk0 + 1, aB);
  vwait6(); SCHED0(); SBAR();

  for (int kk = 0; kk < nchunks; kk += 2) {
    COMP(bufW0, aA);                            // chunk kk
    SCHED0(); SBAR(); SCHED0();
    if (kk + 2 < nchunks) { SW(chunk0 + kk + 2, bufW0); LA(chunk0 + kk + 2, aA); vwait6(); }
    else vwait0();
    SCHED0(); SBAR();                           // bufW1 / aB landed everywhere
    COMP(bufW1, aB);                            // chunk kk+1
    if (kk + 2 < nchunks) {
      SCHED0(); SBAR();                         // all waves done with bufW1
      if (kk + 3 < nchunks) { SW(chunk0 + kk + 3, bufW1); LA(chunk0 + kk + 3, aB); vwait6(); }
      else vwait0();
      SCHED0(); SBAR();                         // bufW0 / aA landed everywhere
    }
  }

  int cols[2]; float bv[2];
  #pragma unroll
  for (int nci = 0; nci < 2; ++nci) {
    int c = n0 + (ch * 2 + nci) * 16 + (lane & 15);
    cols[nci] = c;
    bv[nci] = (bias && c < N) ? bias[c] : 0.f;
  }
  int rb = (lane >> 4) * 4;
  if (CP) {
    float* dst = CP + (size_t)sidx * B_ * N;
    #pragma unroll
    for (int bm = 0; bm < 4; ++bm)
      #pragma unroll
      for (int r = 0; r < 4; ++r) {
        int row = (bm0 + bm) * 16 + rb + r;
        #pragma unroll
        for (int nci = 0; nci < 2; ++nci)
          if (cols[nci] < N) dst[(size_t)row * N + cols[nci]] = acc[bm][nci][r];
      }
  } else {
    #pragma unroll
    for (int bm = 0; bm < 4; ++bm)
      #pragma unroll
      for (int r = 0; r < 4; ++r) {
        int row = (bm0 + bm) * 16 + rb + r;
        #pragma unroll
        for (int nci = 0; nci < 2; ++nci)
          if (cols[nci] < N) Cdir[(size_t)row * N + cols[nci]] = acc[bm][nci][r] + bv[nci];
      }
    if (pms) {
      // per-(row, 32-col-half) partials: index 2*blockIdx.x + ch within 2*nblkx
      #pragma unroll
      for (int bm = 0; bm < 4; ++bm)
        #pragma unroll
        for (int r = 0; r < 4; ++r) {
          int row = (bm0 + bm) * 16 + rb + r;
          float m = -1e30f;
          #pragma unroll
          for (int nci = 0; nci < 2; ++nci)
            if (cols[nci] < N) m = fmaxf(m, acc[bm][nci][r] + bv[nci]);
          #pragma unroll
          for (int off = 8; off; off >>= 1) m = fmaxf(m, __shfl_xor(m, off));
          float e = 0.f;
          #pragma unroll
          for (int nci = 0; nci < 2; ++nci)
            if (cols[nci] < N) e += __expf(acc[bm][nci][r] + bv[nci] - m);
          #pragma unroll
          for (int off = 8; off; off >>= 1) e += __shfl_xor(e, off);
          if ((lane & 15) == 0) {
            size_t o = ((size_t)row * (2 * nblkx) + blockIdx.x * 2 + ch) * 2;
            pms[o] = m; pms[o + 1] = e;
          }
        }
    }
  }
}

// ------------- reduce combine partials (16) + bias + relu -> packed x -------------
__global__ __launch_bounds__(256) void k_reduce_comb(
    const float* __restrict__ parts, const float* __restrict__ bias,
    unsigned short* __restrict__ aX)
{
  int idx = blockIdx.x * 256 + threadIdx.x;  // B_*H_
  int b = idx >> 10, j = idx & (H_ - 1);
  float s = bias[j];
  #pragma unroll
  for (int p = 0; p < 16; ++p) s += parts[(size_t)p * B_ * H_ + idx];
  s = fmaxf(s, 0.f);
  aX[packIdx(b, j)] = f2bf(s);
}

// ------------- GRU gates from split partials (4+4) -> h_new (+packed) -------------
__global__ __launch_bounds__(256) void k_gate(
    const float* __restrict__ giP, const float* __restrict__ ghP,
    const float* __restrict__ b_ih, const float* __restrict__ b_hh,
    const float* __restrict__ hidden, float* __restrict__ hnew,
    unsigned short* __restrict__ aHn)
{
  int idx = blockIdx.x * 256 + threadIdx.x;  // B_*H_
  int b = idx >> 10, j = idx & (H_ - 1);
  size_t base = (size_t)b * 3 * H_;
  float ir = b_ih[j], iz = b_ih[H_ + j], in_ = b_ih[2 * H_ + j];
  float hr = b_hh[j], hz = b_hh[H_ + j], hn = b_hh[2 * H_ + j];
  #pragma unroll
  for (int p = 0; p < 4; ++p) {
    const float* gi = giP + (size_t)p * B_ * 3 * H_ + base;
    const float* gh = ghP + (size_t)p * B_ * 3 * H_ + base;
    ir += gi[j]; iz += gi[H_ + j]; in_ += gi[2 * H_ + j];
    hr += gh[j]; hz += gh[H_ + j]; hn += gh[2 * H_ + j];
  }
  float r = 1.f / (1.f + __expf(-(ir + hr)));
  float z = 1.f / (1.f + __expf(-(iz + hz)));
  float n = tanhf(in_ + r * hn);
  float h = hidden[idx];
  float hv = (1.f - z) * n + z * h;
  hnew[idx] = hv;
  aHn[packIdx(b, j)] = f2bf(hv);
}

// ------------- log_softmax: per-block redundant reduce of pms + subtract -------------
#define SL_ 6283
__global__ __launch_bounds__(256) void k_lsub(
    float* __restrict__ logits, const float* __restrict__ pms, int nblk2)
{
  __shared__ float sm[4], ss[4], sc;
  int b = blockIdx.x, sl = blockIdx.y, t = threadIdx.x;
  float M = -1e30f, S = 0.f;
  for (int i = t; i < nblk2; i += 256) {
    float m = pms[((size_t)b * nblk2 + i) * 2];
    float s = pms[((size_t)b * nblk2 + i) * 2 + 1];
    float nm = fmaxf(M, m);
    S = S * __expf(M - nm) + s * __expf(m - nm);
    M = nm;
  }
  #pragma unroll
  for (int off = 32; off; off >>= 1) {
    float m2 = __shfl_xor(M, off), s2 = __shfl_xor(S, off);
    float nm = fmaxf(M, m2);
    S = S * __expf(M - nm) + s2 * __expf(m2 - nm);
    M = nm;
  }
  if ((t & 63) == 0) { sm[t >> 6] = M; ss[t >> 6] = S; }
  __syncthreads();
  if (t == 0) {
    float Mf = sm[0], Sf = ss[0];
    #pragma unroll
    for (int i = 1; i < 4; ++i) {
      float nm = fmaxf(Mf, sm[i]);
      Sf = Sf * __expf(Mf - nm) + ss[i] * __expf(sm[i] - nm);
      Mf = nm;
    }
    sc = Mf + logf(Sf);
  }
  __syncthreads();
  float c = sc;
  int v0 = sl * SL_;
  int v1 = v0 + SL_; if (v1 > V_) v1 = V_;
  float* row = logits + (size_t)b * V_;
  for (int v = v0 + t; v < v1; v += 256) row[v] -= c;
}

extern "C" void kernel_launch(void* const* d_in, const int* in_sizes, int n_in,
                              void* d_out, int out_size, void* d_ws, size_t ws_size,
                              hipStream_t stream)
{
  const int*   input  = (const int*)d_in[0];
  const float* hidden = (const float*)d_in[1];
  const float* enc    = (const float*)d_in[2];
  const float* emb    = (const float*)d_in[3];
  const float* attn_W = (const float*)d_in[4];
  const float* attn_b = (const float*)d_in[5];
  const float* comb_W = (const float*)d_in[6];
  const float* comb_b = (const float*)d_in[7];
  const float* W_ih   = (const float*)d_in[8];
  const float* W_hh   = (const float*)d_in[9];
  const float* b_ih   = (const float*)d_in[10];
  const float* b_hh   = (const float*)d_in[11];
  const float* out_W  = (const float*)d_in[12];
  const float* out_b  = (const float*)d_in[13];

  float* out    = (float*)d_out;
  float* logits = out;                        // [B,V]
  float* hnew   = out + (size_t)B_ * V_;      // [1,B,H]
  float* attnw  = hnew + (size_t)B_ * H_;     // [B,L]

  const int NBLK = (V_ + 63) / 64;            // 786
  char* ws = (char*)d_ws;
  unsigned short* aXa = (unsigned short*)(ws);                 // 512K
  unsigned short* aH  = (unsigned short*)(ws + 524288);        // 256K
  unsigned short* aX  = (unsigned short*)(ws + 786432);        // 256K
  unsigned short* aHn = (unsigned short*)(ws + 1048576);       // 256K
  float* lbuf  = (float*)(ws + 1310720);                       // 32K
  float* pms   = (float*)(ws + 1343488);                       // 1.61M (128*1572*8B)
  // scratch (aliased): combP (16 x 512K) consumed by k_reduce_comb BEFORE
  // giP/ghP are produced by the gi|gh GEMM.
  float* combP = (float*)(ws + 4194304);                       // 8MB
  float* giP   = (float*)(ws + 4194304);                       // 6MB (aliases combP)
  float* ghP   = (float*)(ws + 4194304 + 6291456);             // 6MB

  // 1. fused: pack embedded+hidden | attention logits
  k_front<<<512 + (B_ * L_) / 4, 256, 0, stream>>>(input, hidden, emb, attn_W, attn_b,
                                                   aXa, aH, lbuf);
  // 2. softmax (redundant per block) + weighted sum; pack into aXa hi
  k_appsm<<<dim3(B_, 4), 256, 0, stream>>>(enc, lbuf, attnw, aXa);
  // 3. combine GEMM: K=2048 (64 chunks), 16 splits x 4 chunks
  k_gemm<<<dim3(16, 16), 256, 0, stream>>>(aXa, nullptr, comb_W, nullptr, nullptr,
                                           nullptr, combP, nullptr, nullptr,
                                           2 * H_, H_, 4, 0, 0);
  // 4. reduce + bias + relu -> packed x
  k_reduce_comb<<<(B_ * H_) / 256, 256, 0, stream>>>(combP, comb_b, aX);
  // 5. fused gi|gh GEMMs: K=1024 (32 chunks), each 4 splits x 8 chunks
  k_gemm<<<dim3(48, 8), 256, 0, stream>>>(aX, aH, W_ih, W_hh, nullptr,
                                          nullptr, giP, ghP, nullptr,
                                          H_, 3 * H_, 8, 4, 0);
  // 6. gates -> h_new (out) + packed h_new
  k_gate<<<(B_ * H_) / 256, 256, 0, stream>>>(giP, ghP, b_ih, b_hh, hidden, hnew, aHn);
  // 7. projection + bias + softmax partials (K=1024 -> 32 chunks, no split)
  k_gemm<<<dim3(NBLK, 1), 256, 0, stream>>>(aHn, nullptr, out_W, nullptr, out_b,
                                            logits, nullptr, nullptr, pms,
                                            H_, V_, 32, 0, NBLK);
  // 8. fused reduce + subtract (2*NBLK partials per row)
  k_lsub<<<dim3(B_, 8), 256, 0, stream>>>(logits, pms, 2 * NBLK);
}